// Round 7
// baseline (2089.701 us; speedup 1.0000x reference)
//
#include <hip/hip_runtime.h>
#include <stdint.h>

#define FPOFF _Pragma("clang fp contract(off)")

// ---------------- problem sizes ----------------
#define ROWS 8192      // N*Ho*Wo = 8*32*32
#define OC 128
#define NS 5           // subarrays
#define SUB 128
#define LP 640         // NS*SUB (padded L)
#define LREAL 576      // C*kh*kw = 64*9
#define NZ 7           // activation bits
#define NK 3           // weight cells
#define NSLOT 21
#define NPTOT 245760   // 3*128*5*128   probs element count
#define NNTOT 1720320  // 7*3*128*5*128 noise element count

#define MMBLOCKS 640   // mm-role blocks FIRST: 128 r-blocks x 5 s
#define QBLOCKS 512    // quant-role blocks after
#define GRIDTOT (MMBLOCKS + QBLOCKS)

// ---------------- ws layout (bytes) ----------------
#define OFF_HDR      0u          // u32[64]: [0]=xmax_enc, pmin[21]@idx8, pmax[21]@idx32
#define OFF_WSCALE   256u        // f32 [NS][OC]
#define OFF_WQ       4096u       // i8  [OC][LP]
#define OFF_CLS      86016u      // u8  [NK][OC][NS][SUB]
#define OFF_INPUTQ   331776u     // u8  [ROWS][LP]
#define OFF_PACKB    5574656u    // u32 [NZ][ROWS][NS][4]
#define OFF_RQ       10162176u   // f32 [NZ][NK][NS][SUB][OC]
#define OFF_PARTA    17043456u   // f32 [NS][ROWS][OC]  ping
#define OFF_PARTB    38014976u   // f32 [NS][ROWS][OC]  pong
#define OFF_OUTD     58986496u   // f32 [ROWS][OC]
#define OFF_OUTACC   63180800u   // f32 [ROWS][OC]  (total ~67.4 MB)

struct U2 { uint32_t x, y; };

__host__ __device__ static inline uint32_t rotl32(uint32_t v, int d){ return (v << d) | (v >> (32 - d)); }

// JAX threefry2x32: 20 rounds, injection every 4. keys (k0,k1), counter (c0,c1).
__host__ __device__ static inline U2 threefry(uint32_t k0, uint32_t k1, uint32_t c0, uint32_t c1){
  uint32_t ks2 = k0 ^ k1 ^ 0x1BD11BDAu;
  uint32_t x0 = c0 + k0, x1 = c1 + k1;
#define TFR(r) { x0 += x1; x1 = rotl32(x1, r); x1 ^= x0; }
  TFR(13) TFR(15) TFR(26) TFR(6)  x0 += k1;  x1 += ks2 + 1u;
  TFR(17) TFR(29) TFR(16) TFR(24) x0 += ks2; x1 += k0 + 2u;
  TFR(13) TFR(15) TFR(26) TFR(6)  x0 += k0;  x1 += k1 + 3u;
  TFR(17) TFR(29) TFR(16) TFR(24) x0 += k1;  x1 += ks2 + 4u;
  TFR(13) TFR(15) TFR(26) TFR(6)  x0 += ks2; x1 += k0 + 5u;
#undef TFR
  U2 r; r.x = x0; r.y = x1; return r;
}

__device__ static inline float u2f(uint32_t b){
  // JAX uniform [0,1): bitcast((bits>>9)|0x3f800000) - 1
  return __uint_as_float((b >> 9) | 0x3F800000u) - 1.0f;
}

// order-preserving float<->uint encode for atomic min/max
__device__ static inline uint32_t encf(float f){
  uint32_t u = __float_as_uint(f);
  return (u & 0x80000000u) ? ~u : (u | 0x80000000u);
}
__device__ static inline float decf(uint32_t e){
  return (e & 0x80000000u) ? __uint_as_float(e & 0x7FFFFFFFu) : __uint_as_float(~e);
}

// XLA/chlo erf_inv f32 (Giles). log1p/sqrt via f64 for correctly-rounded f32.
__device__ static inline float xla_erfinv(float x){
  FPOFF
  float m = x * x;
  float w = -(float)log1p((double)(-m));
  float p;
  if (w < 5.0f){
    w = w - 2.5f;
    p = 2.81022636e-08f;
    p = 3.43273939e-07f  + p * w;
    p = -3.5233877e-06f  + p * w;
    p = -4.39150654e-06f + p * w;
    p = 0.00021858087f   + p * w;
    p = -0.00125372503f  + p * w;
    p = -0.00417768164f  + p * w;
    p = 0.246640727f     + p * w;
    p = 1.50140941f      + p * w;
  } else {
    w = (float)sqrt((double)w) - 3.0f;
    p = -0.000200214257f;
    p = 0.000100950558f  + p * w;
    p = 0.00134934322f   + p * w;
    p = -0.00367342844f  + p * w;
    p = 0.00573950773f   + p * w;
    p = -0.0076224613f   + p * w;
    p = 0.00943887047f   + p * w;
    p = 1.00167406f      + p * w;
    p = 2.83297682f      + p * w;
  }
  return p * x;
}

// ---------------- setup kernels ----------------

__global__ void k_init(uint32_t* hdr){
  int t = threadIdx.x;
  if (t == 0) hdr[0] = 0u;
  if (t < NSLOT){ hdr[8 + t] = 0xFFFFFFFFu; hdr[32 + t] = 0u; }
}

__global__ void k_xmax(const float* __restrict__ x, uint32_t* hdr){
  __shared__ float red[4];
  int t = threadIdx.x;
  const float4* x4 = (const float4*)x;
  int base = blockIdx.x * 1024 + t;
  float m = 0.0f;
#pragma unroll
  for (int i = 0; i < 4; ++i){
    float4 v = x4[base + i * 256];
    m = fmaxf(m, fmaxf(fmaxf(v.x, v.y), fmaxf(v.z, v.w)));
  }
  for (int off = 32; off; off >>= 1) m = fmaxf(m, __shfl_down(m, off));
  if ((t & 63) == 0) red[t >> 6] = m;
  __syncthreads();
  if (t == 0){
    m = fmaxf(fmaxf(red[0], red[1]), fmaxf(red[2], red[3]));
    atomicMax(&hdr[0], encf(m));
  }
}

__global__ void k_wq(const float* __restrict__ wt, float* __restrict__ wscale, int8_t* __restrict__ wq){
  FPOFF
  int s = blockIdx.x, o = blockIdx.y, t = threadIdx.x;  // 64 threads
  int l0 = s * SUB + t, l1 = l0 + 64;
  float w0 = (l0 < LREAL) ? wt[o * LREAL + l0] : 0.f;
  float w1 = (l1 < LREAL) ? wt[o * LREAL + l1] : 0.f;
  float m = fmaxf(fabsf(w0), fabsf(w1));
  for (int off = 32; off; off >>= 1) m = fmaxf(m, __shfl_down(m, off));
  m = __shfl(m, 0);
  float ws = fmaxf(m, 1e-8f) / 127.0f;
  if (t == 0) wscale[s * OC + o] = ws;
  wq[o * LP + l0] = (int8_t)(int)rintf(w0 / ws);
  wq[o * LP + l1] = (int8_t)(int)rintf(w1 / ws);
}

__global__ void k_inputq(const float* __restrict__ x, const uint32_t* __restrict__ hdr, uint8_t* __restrict__ iq){
  FPOFF
  int r = blockIdx.x, t = threadIdx.x;
  float a_scale = fmaxf(decf(hdr[0]), 1e-8f) / 127.0f;
  int n = r >> 10, hw = r & 1023, oh = hw >> 5, ow = hw & 31;
  for (int l = t; l < LP; l += 256){
    float val = 0.f;
    if (l < LREAL){
      int c = l / 9, r9 = l - c * 9, ki = r9 / 3, kj = r9 - ki * 3;
      int ih = oh - 1 + ki, iw = ow - 1 + kj;
      if ((unsigned)ih < 32u && (unsigned)iw < 32u)
        val = x[(((n << 6) + c) << 10) + (ih << 5) + iw];
    }
    iq[r * LP + l] = (uint8_t)(int)rintf(val / a_scale);
  }
}

__global__ void k_pack(const uint8_t* __restrict__ iq, uint32_t* __restrict__ packB){
  int gid = blockIdx.x * 256 + threadIdx.x;
  if (gid >= ROWS * 20) return;
  int r = gid / 20, sw = gid - r * 20;
  const uint4* p4 = (const uint4*)(iq + r * LP + sw * 32);
  uint4 a = p4[0], b2 = p4[1];
  uint32_t wds[8] = {a.x, a.y, a.z, a.w, b2.x, b2.y, b2.z, b2.w};
  uint32_t out[NZ];
#pragma unroll
  for (int z = 0; z < NZ; ++z) out[z] = 0u;
#pragma unroll
  for (int tt = 0; tt < 32; ++tt){
    uint32_t byte = (wds[tt >> 2] >> ((tt & 3) * 8)) & 0xFFu;
#pragma unroll
    for (int z = 0; z < NZ; ++z) out[z] |= ((byte >> z) & 1u) << tt;
  }
#pragma unroll
  for (int z = 0; z < NZ; ++z) packB[(z * ROWS + r) * 20 + sw] = out[z];
}

__global__ void k_cls(uint8_t* __restrict__ cls, uint32_t km0, uint32_t km1){
  int i = blockIdx.x * 256 + threadIdx.x;
  if (i >= NPTOT) return;
  U2 r = threefry(km0, km1, 0u, (uint32_t)i);
  float f = u2f(r.x ^ r.y);
  cls[i] = (f < 0.001f) ? 1 : ((f > 0.999f) ? 2 : 0);
}

__global__ void k_rq(const int8_t* __restrict__ wq, const uint8_t* __restrict__ cls,
                     float* __restrict__ rq, uint32_t kn0, uint32_t kn1){
  FPOFF
  int i = blockIdx.x * 256 + threadIdx.x;
  if (i >= NNTOT) return;
  U2 rr = threefry(kn0, kn1, 0u, (uint32_t)i);
  uint32_t bits = rr.x ^ rr.y;
  // noise flat index [z][k][o][s][j]
  int j = i & 127;
  int t = i >> 7;
  int s = t % 5;
  int t2 = t / 5;
  int o = t2 & 127;
  int t3 = t2 >> 7;
  int k = t3 % 3;
  int z = t3 / 3;
  float f = u2f(bits);
  float u = fmaxf(-0x1.fffffep-1f, f * 2.0f + (-0x1.fffffep-1f));
  float nv = (0x1.6a09e6p+0f * xla_erfinv(u)) * 0.05f;
  int wv = (int)wq[o * LP + s * SUB + j];
  int r0 = wv % 4;  int x1 = (wv - r0) / 4;
  int r1 = x1 % 4;  int x2 = (x1 - r1) / 4;
  int r2 = x2 % 4;
  int rem = (k == 0) ? r0 : ((k == 1) ? r1 : r2);
  float remf = (float)rem;
  float v = remf + remf * nv;
  int c = cls[((k * OC + o) * NS + s) * SUB + j];
  if (c == 1) v = 0.1f;
  else if (c == 2) v = (v > 0.f) ? 1.f : ((v < 0.f) ? -1.f : 0.f);
  rq[(((z * NK + k) * NS + s) * SUB + j) * OC + o] = v;
}

// ---------------- fused mm(slot) + quant(slot-1) ----------------
// blocks [0, MMBLOCKS): mm-role for slot (skipped when slot==21), FIRST.
// blocks [MMBLOCKS, GRIDTOT): quant-role for slot-1 (skipped when slot==0).
// partial ping-pong: mm writes buf[slot&1], quant reads buf[(slot-1)&1].
// mm value path: same-address VMEM global_load_dwordx4 (one coalesced 16B
// L2-hit per load, pipelined via vmcnt). The base pointer is made opaquely
// divergent with a zero VGPR from inline asm so the compiler CANNOT prove
// uniformity and fall back to SMEM s_load (whose out-of-order returns forced
// a lgkmcnt(0) stall per j = the R5 24%-VALUBusy wall; LDS broadcast was the
// R6 LDS-pipe wall).
__global__ __launch_bounds__(256, 4) void k_fused(
    const float* __restrict__ rq, const uint32_t* __restrict__ packB,
    float* __restrict__ partA, float* __restrict__ partB,
    uint32_t* __restrict__ hdr, const float* __restrict__ wscale,
    float* __restrict__ outD, float* __restrict__ outacc,
    float* __restrict__ out, const float* __restrict__ bias, int slot){
  FPOFF
  __shared__ float red[8];
  int bx = blockIdx.x;

  if (bx >= MMBLOCKS){
    // ---- quant-role: slot-1 ----
    if (slot == 0) return;
    int qbx = bx - MMBLOCKS;
    int qslot = slot - 1;
    int z = qslot / 3, k = qslot - z * 3;
    const float* partial = (qslot & 1) ? partB : partA;
    float mn = decf(hdr[8 + qslot]);
    float mx = decf(hdr[32 + qslot]);
    float step = (mx - mn) * 0.03125f;
    if (!(step > 0.f)) step = 1.0f;
    float a_scale = fmaxf(decf(hdr[0]), 1e-8f) / 127.0f;
    int t0 = (qbx << 8) + threadIdx.x;
#pragma unroll
    for (int i = 0; i < 8; ++i){
      int e = t0 + (i << 17);                 // 512*256 = 131072 stride
      int r = e >> 7, o = e & 127;
      float pq = 0.f;
#pragma unroll
      for (int s = 0; s < NS; ++s){
        float v = partial[(size_t)(s * ROWS + r) * OC + o];
        float fidx = floorf((v - mn) / step);
        fidx = fminf(fmaxf(fidx, 0.f), 31.f);
        float qv = fidx * step + mn;
        pq = pq + qv * wscale[s * OC + o];
      }
      if (k == 0) outD[e] = pq;
      else if (k == 1) outD[e] = outD[e] + pq * 4.0f;
      else {
        float tt = outD[e] + pq * 16.0f;
        float contrib = (tt * (float)(1 << z)) * a_scale;
        if (z == 0) outacc[e] = contrib;
        else if (z < 6) outacc[e] = outacc[e] + contrib;
        else {
          float res = outacc[e] + contrib;
          int n = r >> 10, hw = r & 1023;
          out[(((n << 7) + o) << 10) + hw] = res + bias[o];
        }
      }
    }
    return;
  }

  // ---- mm-role: slot ----
  if (slot >= NSLOT) return;
  int mb = bx;                                // [0, 640)
  int s = mb % 5;
  int r0 = (mb / 5) * 64;
  int z = slot / 3;
  float* partial = (slot & 1) ? partB : partA;
  const float* rq_slice = rq + (size_t)slot * NS * SUB * OC;
  const uint32_t* packB_z = packB + (size_t)z * ROWS * 20;

  int tid = threadIdx.x;
  int wave = tid >> 6;
  int lane = tid & 63;
  int r = r0 + lane;                          // lane = row

  // opaque zero VGPR: forces divergent-typed addressing -> VMEM loads
  int vzero;
  asm("v_mov_b32 %0, 0" : "=v"(vzero));
  int o0 = (wave << 5) + vzero;               // o-tile of 32, runtime-uniform

  const uint4* pb = (const uint4*)(packB_z + (size_t)r * 20 + s * 4);
  uint4 bw4 = pb[0];
  uint32_t bw[4] = {bw4.x, bw4.y, bw4.z, bw4.w};

  const float4* rvbase = (const float4*)(rq_slice + (size_t)s * SUB * OC + o0);

  float acc[32];
#pragma unroll
  for (int i2 = 0; i2 < 32; ++i2) acc[i2] = 0.f;

#pragma unroll
  for (int w = 0; w < 4; ++w){
    uint32_t word = bw[w];
#pragma unroll
    for (int j = 0; j < 32; ++j){
      int msk = ((int)(word << (31 - j))) >> 31;                   // 0 / -1
      float bitf = __uint_as_float((uint32_t)msk & 0x3F800000u);   // 0.0f / 1.0f
      const float4* p = rvbase + (size_t)(w * 32 + j) * (OC / 4);  // same-addr VMEM
#pragma unroll
      for (int q = 0; q < 8; ++q){
        float4 v = p[q];                       // global_load_dwordx4, L2-hit
        acc[q * 4 + 0] = __builtin_fmaf(v.x, bitf, acc[q * 4 + 0]);
        acc[q * 4 + 1] = __builtin_fmaf(v.y, bitf, acc[q * 4 + 1]);
        acc[q * 4 + 2] = __builtin_fmaf(v.z, bitf, acc[q * 4 + 2]);
        acc[q * 4 + 3] = __builtin_fmaf(v.w, bitf, acc[q * 4 + 3]);
      }
    }
  }

  // store 32 consecutive o per lane (8 x float4)
  float4* pst = (float4*)(partial + (size_t)(s * ROWS + r) * OC + o0);
#pragma unroll
  for (int q = 0; q < 8; ++q)
    pst[q] = make_float4(acc[q * 4], acc[q * 4 + 1], acc[q * 4 + 2], acc[q * 4 + 3]);

  float mn = acc[0], mx = acc[0];
#pragma unroll
  for (int i2 = 1; i2 < 32; ++i2){ mn = fminf(mn, acc[i2]); mx = fmaxf(mx, acc[i2]); }
  for (int off = 32; off; off >>= 1){
    mn = fminf(mn, __shfl_down(mn, off));
    mx = fmaxf(mx, __shfl_down(mx, off));
  }
  if (lane == 0){ red[wave] = mn; red[4 + wave] = mx; }
  __syncthreads();
  if (tid == 0){
    mn = fminf(fminf(red[0], red[1]), fminf(red[2], red[3]));
    mx = fmaxf(fmaxf(red[4], red[5]), fmaxf(red[6], red[7]));
    atomicMin(&hdr[8 + slot], encf(mn));
    atomicMax(&hdr[32 + slot], encf(mx));
  }
}

// ---------------- host ----------------
extern "C" void kernel_launch(void* const* d_in, const int* in_sizes, int n_in,
                              void* d_out, int out_size, void* d_ws, size_t ws_size,
                              hipStream_t stream){
  const float* x    = (const float*)d_in[0];
  const float* wt   = (const float*)d_in[1];
  const float* bias = (const float*)d_in[2];
  float* out = (float*)d_out;
  char* ws = (char*)d_ws;
  uint32_t* hdr    = (uint32_t*)(ws + OFF_HDR);
  float*    wscale = (float*)(ws + OFF_WSCALE);
  int8_t*   wq     = (int8_t*)(ws + OFF_WQ);
  uint8_t*  cls    = (uint8_t*)(ws + OFF_CLS);
  uint8_t*  iq     = (uint8_t*)(ws + OFF_INPUTQ);
  uint32_t* packB  = (uint32_t*)(ws + OFF_PACKB);
  float*    rq     = (float*)(ws + OFF_RQ);
  float*    partA  = (float*)(ws + OFF_PARTA);
  float*    partB  = (float*)(ws + OFF_PARTB);
  float*    outD   = (float*)(ws + OFF_OUTD);
  float*    outacc = (float*)(ws + OFF_OUTACC);

  // jax.random.key(42) -> (0,42); partitionable (fold-like) split:
  // kmask = both words of threefry(key,(0,0)); knoise = threefry(key,(0,1))
  U2 p0 = threefry(0u, 42u, 0u, 0u);
  U2 p1 = threefry(0u, 42u, 0u, 1u);
  uint32_t km0 = p0.x, km1 = p0.y, kn0 = p1.x, kn1 = p1.y;

  hipLaunchKernelGGL(k_init,   dim3(1),           dim3(64),  0, stream, hdr);
  hipLaunchKernelGGL(k_xmax,   dim3(128),         dim3(256), 0, stream, x, hdr);
  hipLaunchKernelGGL(k_wq,     dim3(5, 128),      dim3(64),  0, stream, wt, wscale, wq);
  hipLaunchKernelGGL(k_inputq, dim3(8192),        dim3(256), 0, stream, x, hdr, iq);
  hipLaunchKernelGGL(k_pack,   dim3(640),         dim3(256), 0, stream, iq, packB);
  hipLaunchKernelGGL(k_cls,    dim3(NPTOT / 256), dim3(256), 0, stream, cls, km0, km1);
  hipLaunchKernelGGL(k_rq,     dim3(NNTOT / 256), dim3(256), 0, stream, wq, cls, rq, kn0, kn1);

  for (int slot = 0; slot <= NSLOT; ++slot){   // 22 fused dispatches
    hipLaunchKernelGGL(k_fused, dim3(GRIDTOT), dim3(256), 0, stream,
                       rq, packB, partA, partB, hdr, wscale,
                       outD, outacc, out, bias, slot);
  }
}

// Round 8
// 976.790 us; speedup vs baseline: 2.1394x; 2.1394x over previous
//
#include <hip/hip_runtime.h>
#include <stdint.h>

#define FPOFF _Pragma("clang fp contract(off)")

// ---------------- problem sizes ----------------
#define ROWS 8192      // N*Ho*Wo = 8*32*32
#define OC 128
#define NS 5           // subarrays
#define SUB 128
#define LP 640         // NS*SUB (padded L)
#define LREAL 576      // C*kh*kw = 64*9
#define NZ 7           // activation bits
#define NK 3           // weight cells
#define NSLOT 21
#define NPTOT 245760   // 3*128*5*128   probs element count
#define NNTOT 1720320  // 7*3*128*5*128 noise element count

#define MMBLOCKS 1280  // mm-role blocks FIRST: 128 r-blocks x 2 o-halves x 5 s
#define QBLOCKS 512    // quant-role blocks after
#define GRIDTOT (MMBLOCKS + QBLOCKS)

// ---------------- ws layout (bytes) ----------------
#define OFF_HDR      0u          // u32[64]: [0]=xmax_enc, pmin[21]@idx8, pmax[21]@idx32
#define OFF_WSCALE   256u        // f32 [NS][OC]
#define OFF_WQ       4096u       // i8  [OC][LP]
#define OFF_CLS      86016u      // u8  [NK][OC][NS][SUB]
#define OFF_INPUTQ   331776u     // u8  [ROWS][LP]
#define OFF_PACKB    5574656u    // u32 [NZ][ROWS][NS][4]
#define OFF_RQ       10162176u   // f32 [NZ][NK][NS][SUB][OC]
#define OFF_PARTA    17043456u   // f32 [NS][ROWS][OC]  ping
#define OFF_PARTB    38014976u   // f32 [NS][ROWS][OC]  pong
#define OFF_OUTD     58986496u   // f32 [ROWS][OC]
#define OFF_OUTACC   63180800u   // f32 [ROWS][OC]  (total ~67.4 MB)

struct U2 { uint32_t x, y; };

__host__ __device__ static inline uint32_t rotl32(uint32_t v, int d){ return (v << d) | (v >> (32 - d)); }

// JAX threefry2x32: 20 rounds, injection every 4. keys (k0,k1), counter (c0,c1).
__host__ __device__ static inline U2 threefry(uint32_t k0, uint32_t k1, uint32_t c0, uint32_t c1){
  uint32_t ks2 = k0 ^ k1 ^ 0x1BD11BDAu;
  uint32_t x0 = c0 + k0, x1 = c1 + k1;
#define TFR(r) { x0 += x1; x1 = rotl32(x1, r); x1 ^= x0; }
  TFR(13) TFR(15) TFR(26) TFR(6)  x0 += k1;  x1 += ks2 + 1u;
  TFR(17) TFR(29) TFR(16) TFR(24) x0 += ks2; x1 += k0 + 2u;
  TFR(13) TFR(15) TFR(26) TFR(6)  x0 += k0;  x1 += k1 + 3u;
  TFR(17) TFR(29) TFR(16) TFR(24) x0 += k1;  x1 += ks2 + 4u;
  TFR(13) TFR(15) TFR(26) TFR(6)  x0 += ks2; x1 += k0 + 5u;
#undef TFR
  U2 r; r.x = x0; r.y = x1; return r;
}

__device__ static inline float u2f(uint32_t b){
  // JAX uniform [0,1): bitcast((bits>>9)|0x3f800000) - 1
  return __uint_as_float((b >> 9) | 0x3F800000u) - 1.0f;
}

// order-preserving float<->uint encode for atomic min/max
__device__ static inline uint32_t encf(float f){
  uint32_t u = __float_as_uint(f);
  return (u & 0x80000000u) ? ~u : (u | 0x80000000u);
}
__device__ static inline float decf(uint32_t e){
  return (e & 0x80000000u) ? __uint_as_float(e & 0x7FFFFFFFu) : __uint_as_float(~e);
}

// XLA/chlo erf_inv f32 (Giles). log1p/sqrt via f64 for correctly-rounded f32.
__device__ static inline float xla_erfinv(float x){
  FPOFF
  float m = x * x;
  float w = -(float)log1p((double)(-m));
  float p;
  if (w < 5.0f){
    w = w - 2.5f;
    p = 2.81022636e-08f;
    p = 3.43273939e-07f  + p * w;
    p = -3.5233877e-06f  + p * w;
    p = -4.39150654e-06f + p * w;
    p = 0.00021858087f   + p * w;
    p = -0.00125372503f  + p * w;
    p = -0.00417768164f  + p * w;
    p = 0.246640727f     + p * w;
    p = 1.50140941f      + p * w;
  } else {
    w = (float)sqrt((double)w) - 3.0f;
    p = -0.000200214257f;
    p = 0.000100950558f  + p * w;
    p = 0.00134934322f   + p * w;
    p = -0.00367342844f  + p * w;
    p = 0.00573950773f   + p * w;
    p = -0.0076224613f   + p * w;
    p = 0.00943887047f   + p * w;
    p = 1.00167406f      + p * w;
    p = 2.83297682f      + p * w;
  }
  return p * x;
}

// ---------------- setup kernels ----------------

__global__ void k_init(uint32_t* hdr){
  int t = threadIdx.x;
  if (t == 0) hdr[0] = 0u;
  if (t < NSLOT){ hdr[8 + t] = 0xFFFFFFFFu; hdr[32 + t] = 0u; }
}

__global__ void k_xmax(const float* __restrict__ x, uint32_t* hdr){
  __shared__ float red[4];
  int t = threadIdx.x;
  const float4* x4 = (const float4*)x;
  int base = blockIdx.x * 1024 + t;
  float m = 0.0f;
#pragma unroll
  for (int i = 0; i < 4; ++i){
    float4 v = x4[base + i * 256];
    m = fmaxf(m, fmaxf(fmaxf(v.x, v.y), fmaxf(v.z, v.w)));
  }
  for (int off = 32; off; off >>= 1) m = fmaxf(m, __shfl_down(m, off));
  if ((t & 63) == 0) red[t >> 6] = m;
  __syncthreads();
  if (t == 0){
    m = fmaxf(fmaxf(red[0], red[1]), fmaxf(red[2], red[3]));
    atomicMax(&hdr[0], encf(m));
  }
}

__global__ void k_wq(const float* __restrict__ wt, float* __restrict__ wscale, int8_t* __restrict__ wq){
  FPOFF
  int s = blockIdx.x, o = blockIdx.y, t = threadIdx.x;  // 64 threads
  int l0 = s * SUB + t, l1 = l0 + 64;
  float w0 = (l0 < LREAL) ? wt[o * LREAL + l0] : 0.f;
  float w1 = (l1 < LREAL) ? wt[o * LREAL + l1] : 0.f;
  float m = fmaxf(fabsf(w0), fabsf(w1));
  for (int off = 32; off; off >>= 1) m = fmaxf(m, __shfl_down(m, off));
  m = __shfl(m, 0);
  float ws = fmaxf(m, 1e-8f) / 127.0f;
  if (t == 0) wscale[s * OC + o] = ws;
  wq[o * LP + l0] = (int8_t)(int)rintf(w0 / ws);
  wq[o * LP + l1] = (int8_t)(int)rintf(w1 / ws);
}

__global__ void k_inputq(const float* __restrict__ x, const uint32_t* __restrict__ hdr, uint8_t* __restrict__ iq){
  FPOFF
  int r = blockIdx.x, t = threadIdx.x;
  float a_scale = fmaxf(decf(hdr[0]), 1e-8f) / 127.0f;
  int n = r >> 10, hw = r & 1023, oh = hw >> 5, ow = hw & 31;
  for (int l = t; l < LP; l += 256){
    float val = 0.f;
    if (l < LREAL){
      int c = l / 9, r9 = l - c * 9, ki = r9 / 3, kj = r9 - ki * 3;
      int ih = oh - 1 + ki, iw = ow - 1 + kj;
      if ((unsigned)ih < 32u && (unsigned)iw < 32u)
        val = x[(((n << 6) + c) << 10) + (ih << 5) + iw];
    }
    iq[r * LP + l] = (uint8_t)(int)rintf(val / a_scale);
  }
}

__global__ void k_pack(const uint8_t* __restrict__ iq, uint32_t* __restrict__ packB){
  int gid = blockIdx.x * 256 + threadIdx.x;
  if (gid >= ROWS * 20) return;
  int r = gid / 20, sw = gid - r * 20;
  const uint4* p4 = (const uint4*)(iq + r * LP + sw * 32);
  uint4 a = p4[0], b2 = p4[1];
  uint32_t wds[8] = {a.x, a.y, a.z, a.w, b2.x, b2.y, b2.z, b2.w};
  uint32_t out[NZ];
#pragma unroll
  for (int z = 0; z < NZ; ++z) out[z] = 0u;
#pragma unroll
  for (int tt = 0; tt < 32; ++tt){
    uint32_t byte = (wds[tt >> 2] >> ((tt & 3) * 8)) & 0xFFu;
#pragma unroll
    for (int z = 0; z < NZ; ++z) out[z] |= ((byte >> z) & 1u) << tt;
  }
#pragma unroll
  for (int z = 0; z < NZ; ++z) packB[(z * ROWS + r) * 20 + sw] = out[z];
}

__global__ void k_cls(uint8_t* __restrict__ cls, uint32_t km0, uint32_t km1){
  int i = blockIdx.x * 256 + threadIdx.x;
  if (i >= NPTOT) return;
  U2 r = threefry(km0, km1, 0u, (uint32_t)i);
  float f = u2f(r.x ^ r.y);
  cls[i] = (f < 0.001f) ? 1 : ((f > 0.999f) ? 2 : 0);
}

__global__ void k_rq(const int8_t* __restrict__ wq, const uint8_t* __restrict__ cls,
                     float* __restrict__ rq, uint32_t kn0, uint32_t kn1){
  FPOFF
  int i = blockIdx.x * 256 + threadIdx.x;
  if (i >= NNTOT) return;
  U2 rr = threefry(kn0, kn1, 0u, (uint32_t)i);
  uint32_t bits = rr.x ^ rr.y;
  // noise flat index [z][k][o][s][j]
  int j = i & 127;
  int t = i >> 7;
  int s = t % 5;
  int t2 = t / 5;
  int o = t2 & 127;
  int t3 = t2 >> 7;
  int k = t3 % 3;
  int z = t3 / 3;
  float f = u2f(bits);
  float u = fmaxf(-0x1.fffffep-1f, f * 2.0f + (-0x1.fffffep-1f));
  float nv = (0x1.6a09e6p+0f * xla_erfinv(u)) * 0.05f;
  int wv = (int)wq[o * LP + s * SUB + j];
  int r0 = wv % 4;  int x1 = (wv - r0) / 4;
  int r1 = x1 % 4;  int x2 = (x1 - r1) / 4;
  int r2 = x2 % 4;
  int rem = (k == 0) ? r0 : ((k == 1) ? r1 : r2);
  float remf = (float)rem;
  float v = remf + remf * nv;
  int c = cls[((k * OC + o) * NS + s) * SUB + j];
  if (c == 1) v = 0.1f;
  else if (c == 2) v = (v > 0.f) ? 1.f : ((v < 0.f) ? -1.f : 0.f);
  rq[(((z * NK + k) * NS + s) * SUB + j) * OC + o] = v;
}

// ---------------- fused mm(slot) + quant(slot-1) ----------------
// blocks [0, MMBLOCKS): mm-role for slot (skipped when slot==21), FIRST.
//   16-wide o-tile per wave -> 5120 mm waves = 20/CU (the R4-proven occupancy;
//   R5's 32-wide halved waves to 10/CU and lost to the SMEM drain stall).
//   2-j s_load pairing: issue both dwordx16 loads, one lgkmcnt drain, then
//   2x(16 fmac + 2 bit ops) -> halves stall count per wave.
// blocks [MMBLOCKS, GRIDTOT): quant-role for slot-1 (skipped when slot==0).
// partial ping-pong: mm writes buf[slot&1], quant reads buf[(slot-1)&1].
__global__ __launch_bounds__(256, 8) void k_fused(
    const float* __restrict__ rq, const uint32_t* __restrict__ packB,
    float* __restrict__ partA, float* __restrict__ partB,
    uint32_t* __restrict__ hdr, const float* __restrict__ wscale,
    float* __restrict__ outD, float* __restrict__ outacc,
    float* __restrict__ out, const float* __restrict__ bias, int slot){
  FPOFF
  __shared__ float red[8];
  int bx = blockIdx.x;

  if (bx >= MMBLOCKS){
    // ---- quant-role: slot-1 ----
    if (slot == 0) return;
    int qbx = bx - MMBLOCKS;
    int qslot = slot - 1;
    int z = qslot / 3, k = qslot - z * 3;
    const float* partial = (qslot & 1) ? partB : partA;
    float mn = decf(hdr[8 + qslot]);
    float mx = decf(hdr[32 + qslot]);
    float step = (mx - mn) * 0.03125f;
    if (!(step > 0.f)) step = 1.0f;
    float a_scale = fmaxf(decf(hdr[0]), 1e-8f) / 127.0f;
    int t0 = (qbx << 8) + threadIdx.x;
#pragma unroll
    for (int i = 0; i < 8; ++i){
      int e = t0 + (i << 17);                 // 512*256 = 131072 stride
      int r = e >> 7, o = e & 127;
      float pq = 0.f;
#pragma unroll
      for (int s = 0; s < NS; ++s){
        float v = partial[(size_t)(s * ROWS + r) * OC + o];
        float fidx = floorf((v - mn) / step);
        fidx = fminf(fmaxf(fidx, 0.f), 31.f);
        float qv = fidx * step + mn;
        pq = pq + qv * wscale[s * OC + o];
      }
      if (k == 0) outD[e] = pq;
      else if (k == 1) outD[e] = outD[e] + pq * 4.0f;
      else {
        float tt = outD[e] + pq * 16.0f;
        float contrib = (tt * (float)(1 << z)) * a_scale;
        if (z == 0) outacc[e] = contrib;
        else if (z < 6) outacc[e] = outacc[e] + contrib;
        else {
          float res = outacc[e] + contrib;
          int n = r >> 10, hw = r & 1023;
          out[(((n << 7) + o) << 10) + hw] = res + bias[o];
        }
      }
    }
    return;
  }

  // ---- mm-role: slot ----
  if (slot >= NSLOT) return;
  int mb = bx;                                // [0, 1280)
  int s = mb % 5;
  int t = mb / 5;                             // [0, 256)
  int r0 = (t >> 1) * 64;
  int oh = t & 1;
  int z = slot / 3;
  float* partial = (slot & 1) ? partB : partA;
  const float* rq_slice = rq + (size_t)slot * NS * SUB * OC;
  const uint32_t* packB_z = packB + (size_t)z * ROWS * 20;

  int tid = threadIdx.x;
  int wave = tid >> 6;
  int lane = tid & 63;
  int r = r0 + lane;                          // lane = row
  int o0 = __builtin_amdgcn_readfirstlane(oh * 64 + (wave << 4));  // 16-wide o-tile

  const uint4* pb = (const uint4*)(packB_z + (size_t)r * 20 + s * 4);
  uint4 bw4 = pb[0];
  uint32_t bw[4] = {bw4.x, bw4.y, bw4.z, bw4.w};

  const float4* rvbase = (const float4*)(rq_slice + (size_t)s * SUB * OC + o0);

  float acc[16];
#pragma unroll
  for (int i2 = 0; i2 < 16; ++i2) acc[i2] = 0.f;

#pragma unroll
  for (int w = 0; w < 4; ++w){
    uint32_t word = bw[w];
#pragma unroll
    for (int jp = 0; jp < 16; ++jp){          // pairs: j0 = 2*jp, j1 = 2*jp+1
      int j0 = jp * 2;
      const float4* p0 = rvbase + (size_t)(w * 32 + j0) * (OC / 4);
      const float4* p1 = p0 + (OC / 4);
      // both pair loads issued before use -> one lgkmcnt drain per pair
      float4 a0 = p0[0], a1 = p0[1], a2 = p0[2], a3 = p0[3];
      float4 b0 = p1[0], b1 = p1[1], b2 = p1[2], b3 = p1[3];
      int m0 = ((int)(word << (31 - j0))) >> 31;
      float f0 = __uint_as_float((uint32_t)m0 & 0x3F800000u);
      int m1 = ((int)(word << (30 - j0))) >> 31;
      float f1 = __uint_as_float((uint32_t)m1 & 0x3F800000u);
      acc[0]  = __builtin_fmaf(a0.x, f0, acc[0]);
      acc[1]  = __builtin_fmaf(a0.y, f0, acc[1]);
      acc[2]  = __builtin_fmaf(a0.z, f0, acc[2]);
      acc[3]  = __builtin_fmaf(a0.w, f0, acc[3]);
      acc[4]  = __builtin_fmaf(a1.x, f0, acc[4]);
      acc[5]  = __builtin_fmaf(a1.y, f0, acc[5]);
      acc[6]  = __builtin_fmaf(a1.z, f0, acc[6]);
      acc[7]  = __builtin_fmaf(a1.w, f0, acc[7]);
      acc[8]  = __builtin_fmaf(a2.x, f0, acc[8]);
      acc[9]  = __builtin_fmaf(a2.y, f0, acc[9]);
      acc[10] = __builtin_fmaf(a2.z, f0, acc[10]);
      acc[11] = __builtin_fmaf(a2.w, f0, acc[11]);
      acc[12] = __builtin_fmaf(a3.x, f0, acc[12]);
      acc[13] = __builtin_fmaf(a3.y, f0, acc[13]);
      acc[14] = __builtin_fmaf(a3.z, f0, acc[14]);
      acc[15] = __builtin_fmaf(a3.w, f0, acc[15]);
      acc[0]  = __builtin_fmaf(b0.x, f1, acc[0]);
      acc[1]  = __builtin_fmaf(b0.y, f1, acc[1]);
      acc[2]  = __builtin_fmaf(b0.z, f1, acc[2]);
      acc[3]  = __builtin_fmaf(b0.w, f1, acc[3]);
      acc[4]  = __builtin_fmaf(b1.x, f1, acc[4]);
      acc[5]  = __builtin_fmaf(b1.y, f1, acc[5]);
      acc[6]  = __builtin_fmaf(b1.z, f1, acc[6]);
      acc[7]  = __builtin_fmaf(b1.w, f1, acc[7]);
      acc[8]  = __builtin_fmaf(b2.x, f1, acc[8]);
      acc[9]  = __builtin_fmaf(b2.y, f1, acc[9]);
      acc[10] = __builtin_fmaf(b2.z, f1, acc[10]);
      acc[11] = __builtin_fmaf(b2.w, f1, acc[11]);
      acc[12] = __builtin_fmaf(b3.x, f1, acc[12]);
      acc[13] = __builtin_fmaf(b3.y, f1, acc[13]);
      acc[14] = __builtin_fmaf(b3.z, f1, acc[14]);
      acc[15] = __builtin_fmaf(b3.w, f1, acc[15]);
    }
  }

  // store 16 consecutive o per lane (4 x float4)
  float4* pst = (float4*)(partial + (size_t)(s * ROWS + r) * OC + o0);
#pragma unroll
  for (int q = 0; q < 4; ++q)
    pst[q] = make_float4(acc[q * 4], acc[q * 4 + 1], acc[q * 4 + 2], acc[q * 4 + 3]);

  float mn = acc[0], mx = acc[0];
#pragma unroll
  for (int i2 = 1; i2 < 16; ++i2){ mn = fminf(mn, acc[i2]); mx = fmaxf(mx, acc[i2]); }
  for (int off = 32; off; off >>= 1){
    mn = fminf(mn, __shfl_down(mn, off));
    mx = fmaxf(mx, __shfl_down(mx, off));
  }
  if (lane == 0){ red[wave] = mn; red[4 + wave] = mx; }
  __syncthreads();
  if (tid == 0){
    mn = fminf(fminf(red[0], red[1]), fminf(red[2], red[3]));
    mx = fmaxf(fmaxf(red[4], red[5]), fmaxf(red[6], red[7]));
    atomicMin(&hdr[8 + slot], encf(mn));
    atomicMax(&hdr[32 + slot], encf(mx));
  }
}

// ---------------- host ----------------
extern "C" void kernel_launch(void* const* d_in, const int* in_sizes, int n_in,
                              void* d_out, int out_size, void* d_ws, size_t ws_size,
                              hipStream_t stream){
  const float* x    = (const float*)d_in[0];
  const float* wt   = (const float*)d_in[1];
  const float* bias = (const float*)d_in[2];
  float* out = (float*)d_out;
  char* ws = (char*)d_ws;
  uint32_t* hdr    = (uint32_t*)(ws + OFF_HDR);
  float*    wscale = (float*)(ws + OFF_WSCALE);
  int8_t*   wq     = (int8_t*)(ws + OFF_WQ);
  uint8_t*  cls    = (uint8_t*)(ws + OFF_CLS);
  uint8_t*  iq     = (uint8_t*)(ws + OFF_INPUTQ);
  uint32_t* packB  = (uint32_t*)(ws + OFF_PACKB);
  float*    rq     = (float*)(ws + OFF_RQ);
  float*    partA  = (float*)(ws + OFF_PARTA);
  float*    partB  = (float*)(ws + OFF_PARTB);
  float*    outD   = (float*)(ws + OFF_OUTD);
  float*    outacc = (float*)(ws + OFF_OUTACC);

  // jax.random.key(42) -> (0,42); partitionable (fold-like) split:
  // kmask = both words of threefry(key,(0,0)); knoise = threefry(key,(0,1))
  U2 p0 = threefry(0u, 42u, 0u, 0u);
  U2 p1 = threefry(0u, 42u, 0u, 1u);
  uint32_t km0 = p0.x, km1 = p0.y, kn0 = p1.x, kn1 = p1.y;

  hipLaunchKernelGGL(k_init,   dim3(1),           dim3(64),  0, stream, hdr);
  hipLaunchKernelGGL(k_xmax,   dim3(128),         dim3(256), 0, stream, x, hdr);
  hipLaunchKernelGGL(k_wq,     dim3(5, 128),      dim3(64),  0, stream, wt, wscale, wq);
  hipLaunchKernelGGL(k_inputq, dim3(8192),        dim3(256), 0, stream, x, hdr, iq);
  hipLaunchKernelGGL(k_pack,   dim3(640),         dim3(256), 0, stream, iq, packB);
  hipLaunchKernelGGL(k_cls,    dim3(NPTOT / 256), dim3(256), 0, stream, cls, km0, km1);
  hipLaunchKernelGGL(k_rq,     dim3(NNTOT / 256), dim3(256), 0, stream, wq, cls, rq, kn0, kn1);

  for (int slot = 0; slot <= NSLOT; ++slot){   // 22 fused dispatches
    hipLaunchKernelGGL(k_fused, dim3(GRIDTOT), dim3(256), 0, stream,
                       rq, packB, partA, partB, hdr, wscale,
                       outD, outacc, out, bias, slot);
  }
}